// Round 1
// baseline (449.117 us; speedup 1.0000x reference)
//
#include <hip/hip_runtime.h>
#include <math.h>

#define S_TOK 65536
#define H_DIM 768
#define T_TYPES 6
#define K_TOP 3
#define WIN 15
#define NBLK1 512
#define NWAVES (NBLK1 * 4)
#define ROWS_PER_WAVE (S_TOK / NWAVES)   // 32

// ---------------------------------------------------------------------------
// Kernel 1: one pass over token_embeds (192 MiB). Wave-per-row:
//   lane loads h = 4*(lane+64j)+c, j=0..2, c=0..3 (3x float4, coalesced)
//   144 weights/lane live in VGPRs (W_start & W_end columns for its h's)
//   butterfly-reduce 12 accumulators across the 64 lanes
//   lanes 0..11 store start/end scores in [T][S] layout
//   per-lane pooled column partial sums -> LDS block reduce -> per-block partial
// ---------------------------------------------------------------------------
__global__ __launch_bounds__(256, 2) void k_scores(
    const float* __restrict__ emb,
    const float* __restrict__ Wstart, const float* __restrict__ bstart,
    const float* __restrict__ Wend,   const float* __restrict__ bend,
    float* __restrict__ startS, float* __restrict__ endS,
    float* __restrict__ pooledPart)
{
    const int lane = threadIdx.x & 63;
    const int wib  = threadIdx.x >> 6;           // wave in block, 0..3
    const int wave = blockIdx.x * 4 + wib;

    // preload weights for this lane's h positions (once)
    float wS[3][4][T_TYPES], wE[3][4][T_TYPES];
#pragma unroll
    for (int j = 0; j < 3; ++j)
#pragma unroll
        for (int c = 0; c < 4; ++c) {
            const int h = 4 * (lane + 64 * j) + c;
#pragma unroll
            for (int t = 0; t < T_TYPES; ++t) {
                wS[j][c][t] = Wstart[h * T_TYPES + t];
                wE[j][c][t] = Wend  [h * T_TYPES + t];
            }
        }

    float myBias = 0.0f;
    if (lane < T_TYPES)            myBias = bstart[lane];
    else if (lane < 2 * T_TYPES)   myBias = bend[lane - T_TYPES];

    float pool[3][4] = {};

    const int r0 = wave * ROWS_PER_WAVE;
    for (int r = r0; r < r0 + ROWS_PER_WAVE; ++r) {
        const float4* rp = (const float4*)(emb + (size_t)r * H_DIM);
        float4 ee[3];
        ee[0] = rp[lane];
        ee[1] = rp[lane + 64];
        ee[2] = rp[lane + 128];

        float acc[12];
#pragma unroll
        for (int a = 0; a < 12; ++a) acc[a] = 0.0f;

#pragma unroll
        for (int j = 0; j < 3; ++j) {
            const float ev[4] = {ee[j].x, ee[j].y, ee[j].z, ee[j].w};
#pragma unroll
            for (int c = 0; c < 4; ++c) {
                const float v = ev[c];
                pool[j][c] += v;
#pragma unroll
                for (int t = 0; t < T_TYPES; ++t) {
                    acc[t]            = fmaf(v, wS[j][c][t], acc[t]);
                    acc[T_TYPES + t]  = fmaf(v, wE[j][c][t], acc[T_TYPES + t]);
                }
            }
        }

        // butterfly reduce all 12 accumulators over 64 lanes
#pragma unroll
        for (int a = 0; a < 12; ++a) {
#pragma unroll
            for (int m = 1; m < 64; m <<= 1)
                acc[a] += __shfl_xor(acc[a], m, 64);
        }

        if (lane < 12) {
            float v = acc[0];
#pragma unroll
            for (int a = 1; a < 12; ++a) v = (lane == a) ? acc[a] : v;
            v += myBias;
            float* p = (lane < T_TYPES)
                ? (startS + (size_t)lane * S_TOK + r)
                : (endS + (size_t)(lane - T_TYPES) * S_TOK + r);
            *p = v;
        }
    }

    // block-reduce pooled partials
    __shared__ float lds[4][H_DIM];   // 12 KiB
#pragma unroll
    for (int j = 0; j < 3; ++j)
#pragma unroll
        for (int c = 0; c < 4; ++c)
            lds[wib][4 * (lane + 64 * j) + c] = pool[j][c];
    __syncthreads();
    for (int h = threadIdx.x; h < H_DIM; h += 256) {
        pooledPart[(size_t)blockIdx.x * H_DIM + h] =
            lds[0][h] + lds[1][h] + lds[2][h] + lds[3][h];
    }
}

// ---------------------------------------------------------------------------
// top-3 insert with jnp tie-breaking (equal value -> lower index wins)
// ---------------------------------------------------------------------------
__device__ __forceinline__ void top3_insert(float v, int i,
    float& v0, float& v1, float& v2, int& i0, int& i1, int& i2)
{
    if (v > v0 || (v == v0 && i < i0)) {
        v2 = v1; i2 = i1; v1 = v0; i1 = i0; v0 = v; i0 = i;
    } else if (v > v1 || (v == v1 && i < i1)) {
        v2 = v1; i2 = i1; v1 = v; i1 = i;
    } else if (v > v2 || (v == v2 && i < i2)) {
        v2 = v; i2 = i;
    }
}

// ---------------------------------------------------------------------------
// Kernel 2: one block per type. Pass 1: max. Pass 2: sumexp + per-thread top3.
// Butterfly + LDS merge. Writes res[t*8] = {v0,v1,v2, i0,i1,i2, M, sumexp}.
// ---------------------------------------------------------------------------
__global__ __launch_bounds__(1024) void k_softtop(
    const float* __restrict__ startS, float* __restrict__ res)
{
    const int t = blockIdx.x;
    const float* col = startS + (size_t)t * S_TOK;
    const int tid = threadIdx.x;

    // pass 1: block max
    float m = -3.402823466e38f;
    for (int s = tid; s < S_TOK; s += 1024) m = fmaxf(m, col[s]);
#pragma unroll
    for (int msk = 1; msk < 64; msk <<= 1) m = fmaxf(m, __shfl_xor(m, msk, 64));
    __shared__ float wred[16];
    __shared__ float Msh;
    if ((tid & 63) == 0) wred[tid >> 6] = m;
    __syncthreads();
    if (tid == 0) {
        float M = wred[0];
        for (int w = 1; w < 16; ++w) M = fmaxf(M, wred[w]);
        Msh = M;
    }
    __syncthreads();
    const float M = Msh;

    // pass 2: sumexp + local top3 (s ascending per thread -> strict > keeps
    // the earliest index, matching top_k tie-breaking)
    float se = 0.0f;
    float v0 = -3.402823466e38f, v1 = v0, v2 = v0;
    int   i0 = -1, i1 = -1, i2 = -1;
    for (int s = tid; s < S_TOK; s += 1024) {
        const float v = col[s];
        se += expf(v - M);
        if (v > v2) {
            if (v > v0)      { v2=v1;i2=i1; v1=v0;i1=i0; v0=v;i0=s; }
            else if (v > v1) { v2=v1;i2=i1; v1=v; i1=s; }
            else             { v2=v; i2=s; }
        }
    }

    // wave butterfly merge (groups are disjoint cosets -> no duplicates)
#pragma unroll
    for (int msk = 1; msk < 64; msk <<= 1) {
        const float o0 = __shfl_xor(v0, msk, 64);
        const float o1 = __shfl_xor(v1, msk, 64);
        const float o2 = __shfl_xor(v2, msk, 64);
        const int   j0 = __shfl_xor(i0, msk, 64);
        const int   j1 = __shfl_xor(i1, msk, 64);
        const int   j2 = __shfl_xor(i2, msk, 64);
        se += __shfl_xor(se, msk, 64);
        top3_insert(o0, j0, v0, v1, v2, i0, i1, i2);
        top3_insert(o1, j1, v0, v1, v2, i0, i1, i2);
        top3_insert(o2, j2, v0, v1, v2, i0, i1, i2);
    }

    __shared__ float sv[16][3];
    __shared__ int   si[16][3];
    __shared__ float ssum[16];
    if ((tid & 63) == 0) {
        const int w = tid >> 6;
        sv[w][0] = v0; sv[w][1] = v1; sv[w][2] = v2;
        si[w][0] = i0; si[w][1] = i1; si[w][2] = i2;
        ssum[w] = se;
    }
    __syncthreads();
    if (tid == 0) {
        float V0 = -3.402823466e38f, V1 = V0, V2 = V0;
        int   I0 = -1, I1 = -1, I2 = -1;
        float SE = 0.0f;
        for (int w = 0; w < 16; ++w) {
            SE += ssum[w];
            top3_insert(sv[w][0], si[w][0], V0, V1, V2, I0, I1, I2);
            top3_insert(sv[w][1], si[w][1], V0, V1, V2, I0, I1, I2);
            top3_insert(sv[w][2], si[w][2], V0, V1, V2, I0, I1, I2);
        }
        float* r = res + t * 8;
        r[0] = V0; r[1] = V1; r[2] = V2;
        r[3] = (float)I0; r[4] = (float)I1; r[5] = (float)I2;
        r[6] = M; r[7] = SE;
    }
}

// ---------------------------------------------------------------------------
// Kernel 3: single block. pooled reduce -> GELU MLP -> sigmoid; softmax
// top-vals; window argmax over end scores; write all 72 f32 outputs.
// ---------------------------------------------------------------------------
__global__ __launch_bounds__(256) void k_final(
    const float* __restrict__ pooledPart,
    const float* __restrict__ W1, const float* __restrict__ b1,
    const float* __restrict__ W2, const float* __restrict__ b2,
    const float* __restrict__ endS, const float* __restrict__ res,
    float* __restrict__ out)
{
    const int tid = threadIdx.x;
    __shared__ float pooled[H_DIM];
    for (int h = tid; h < H_DIM; h += 256) {
        float s = 0.0f;
        for (int b = 0; b < NBLK1; ++b) s += pooledPart[(size_t)b * H_DIM + h];
        pooled[h] = s * (1.0f / (float)S_TOK);
    }
    __syncthreads();

    __shared__ float hdn[64];
    if (tid < 64) {
        float z = b1[tid];
        for (int h = 0; h < H_DIM; ++h) z = fmaf(pooled[h], W1[h * 64 + tid], z);
        // exact GELU: 0.5*x*(1+erf(x/sqrt(2)))
        hdn[tid] = 0.5f * z * (1.0f + erff(z * 0.7071067811865475f));
    }
    __syncthreads();

    __shared__ float tconf[T_TYPES];
    if (tid < T_TYPES) {
        float z = b2[tid];
        for (int i = 0; i < 64; ++i) z = fmaf(hdn[i], W2[i * T_TYPES + tid], z);
        tconf[tid] = 1.0f / (1.0f + expf(-z));
    }
    __syncthreads();

    if (tid < T_TYPES * K_TOP) {
        const int t = tid / K_TOP;
        const int k = tid % K_TOP;
        const float* r = res + t * 8;
        const float vraw = r[k];
        const int   idx  = (int)r[3 + k];
        const float M    = r[6];
        const float SE   = r[7];
        const float prob = expf(vraw - M) / SE;

        const float* ecol = endS + (size_t)t * S_TOK;
        float best = -3.402823466e38f;
        int   boff = 0;
#pragma unroll
        for (int w = 0; w < WIN; ++w) {
            const int pos = idx + w;
            if (pos < S_TOK) {                 // out-of-range -> -inf -> skip
                const float ev = ecol[pos];
                if (ev > best) { best = ev; boff = w; }  // strict > = first max
            }
        }
        const float tc = tconf[t];
        const bool valid = (tc >= 0.3f) && (prob >= 0.15f);
        out[tid]      = valid ? prob * tc : 0.0f;   // conf
        out[18 + tid] = (float)idx;                 // starts
        out[36 + tid] = (float)(idx + boff + 1);    // ends
        out[54 + tid] = valid ? 1.0f : 0.0f;        // valid
    }
}

extern "C" void kernel_launch(void* const* d_in, const int* in_sizes, int n_in,
                              void* d_out, int out_size, void* d_ws, size_t ws_size,
                              hipStream_t stream)
{
    const float* emb    = (const float*)d_in[0];
    const float* Wstart = (const float*)d_in[1];
    const float* bstart = (const float*)d_in[2];
    const float* Wend   = (const float*)d_in[3];
    const float* bend   = (const float*)d_in[4];
    const float* W1     = (const float*)d_in[5];
    const float* b1     = (const float*)d_in[6];
    const float* W2     = (const float*)d_in[7];
    const float* b2     = (const float*)d_in[8];
    float* out = (float*)d_out;

    // workspace layout (floats):
    //   startS: T*S        (1.5 MB)
    //   endS:   T*S        (1.5 MB)
    //   pooledPart: NBLK1*H (1.5 MB)
    //   res:    T*8
    float* ws     = (float*)d_ws;
    float* startS = ws;
    float* endS   = ws + (size_t)T_TYPES * S_TOK;
    float* pp     = ws + (size_t)2 * T_TYPES * S_TOK;
    float* res    = pp + (size_t)NBLK1 * H_DIM;

    k_scores<<<NBLK1, 256, 0, stream>>>(emb, Wstart, bstart, Wend, bend,
                                        startS, endS, pp);
    k_softtop<<<T_TYPES, 1024, 0, stream>>>(startS, res);
    k_final<<<1, 256, 0, stream>>>(pp, W1, b1, W2, b2, endS, res, out);
}

// Round 2
// 349.151 us; speedup vs baseline: 1.2863x; 1.2863x over previous
//
#include <hip/hip_runtime.h>
#include <math.h>

#define S_TOK 65536
#define H_DIM 768
#define T_TYPES 6
#define K_TOP 3
#define WIN 15
#define NBLK1 512
#define NWAVES (NBLK1 * 4)               // 2048
#define ROWS_PER_WAVE (S_TOK / NWAVES)   // 32
#define POOL_CHUNKS 8
#define BLK_PER_CHUNK (NBLK1 / POOL_CHUNKS)  // 64

// ---------------------------------------------------------------------------
// top-3 insert with jnp tie-breaking (equal value -> lower index wins)
// ---------------------------------------------------------------------------
__device__ __forceinline__ void top3_insert(float v, int i,
    float& v0, float& v1, float& v2, int& i0, int& i1, int& i2)
{
    if (v > v0 || (v == v0 && i < i0)) {
        v2 = v1; i2 = i1; v1 = v0; i1 = i0; v0 = v; i0 = i;
    } else if (v > v1 || (v == v1 && i < i1)) {
        v2 = v1; i2 = i1; v1 = v; i1 = i;
    } else if (v > v2 || (v == v2 && i < i2)) {
        v2 = v; i2 = i;
    }
}

// merge online-softmax+top3 state (M,se,top3) with another state
__device__ __forceinline__ void merge_state(
    float& M, float& se, float& v0, float& v1, float& v2,
    int& i0, int& i1, int& i2,
    float Mb, float seb, float w0, float w1, float w2,
    int j0, int j1, int j2)
{
    const float Mn = fmaxf(M, Mb);
    se = se * expf(M - Mn) + seb * expf(Mb - Mn);
    M = Mn;
    top3_insert(w0, j0, v0, v1, v2, i0, i1, i2);
    top3_insert(w1, j1, v0, v1, v2, i0, i1, i2);
    top3_insert(w2, j2, v0, v1, v2, i0, i1, i2);
}

// ---------------------------------------------------------------------------
// Kernel 1: single pass over token_embeds (192 MiB). Wave-per-row with
// explicit next-row prefetch. Per row: 144 FMA + 64-lane butterfly of 12
// accumulators (bit-identical score values to the verified round-1 kernel).
// Lanes 0..5 keep a running online-softmax + top-3 state for their type;
// lanes 6..11 store end scores [T][S]. Per-block pooled partials as before.
// startS is never materialized.
// ---------------------------------------------------------------------------
__global__ __launch_bounds__(256, 2) void k_scores(
    const float* __restrict__ emb,
    const float* __restrict__ Wstart, const float* __restrict__ bstart,
    const float* __restrict__ Wend,   const float* __restrict__ bend,
    float* __restrict__ endS,
    float* __restrict__ partials,     // [NWAVES][T_TYPES][8]
    float* __restrict__ pooledPart)   // [NBLK1][H_DIM]
{
    const int lane = threadIdx.x & 63;
    const int wib  = threadIdx.x >> 6;
    const int wave = blockIdx.x * 4 + wib;

    float wS[3][4][T_TYPES], wE[3][4][T_TYPES];
#pragma unroll
    for (int j = 0; j < 3; ++j)
#pragma unroll
        for (int c = 0; c < 4; ++c) {
            const int h = 4 * (lane + 64 * j) + c;
#pragma unroll
            for (int t = 0; t < T_TYPES; ++t) {
                wS[j][c][t] = Wstart[h * T_TYPES + t];
                wE[j][c][t] = Wend  [h * T_TYPES + t];
            }
        }

    float myBias = 0.0f;
    if (lane < T_TYPES)            myBias = bstart[lane];
    else if (lane < 2 * T_TYPES)   myBias = bend[lane - T_TYPES];

    float pool[3][4] = {};

    // online softmax + top3 state (meaningful on lanes 0..5 only)
    float M  = -3.402823466e38f, se = 0.0f;
    float v0 = -3.402823466e38f, v1 = v0, v2 = v0;
    int   i0 = -1, i1 = -1, i2 = -1;

    const int r0 = wave * ROWS_PER_WAVE;
    const float4* rowp = (const float4*)emb + (size_t)r0 * (H_DIM / 4);
    float4 c0 = rowp[lane], c1 = rowp[lane + 64], c2 = rowp[lane + 128];

    for (int r = r0; r < r0 + ROWS_PER_WAVE; ++r) {
        const float4* nextp = rowp + ((r + 1 < S_TOK) ? (H_DIM / 4) : 0);
        float4 n0 = nextp[lane], n1 = nextp[lane + 64], n2 = nextp[lane + 128];

        float acc[12];
#pragma unroll
        for (int a = 0; a < 12; ++a) acc[a] = 0.0f;

        const float4 ee[3] = {c0, c1, c2};
#pragma unroll
        for (int j = 0; j < 3; ++j) {
            const float ev[4] = {ee[j].x, ee[j].y, ee[j].z, ee[j].w};
#pragma unroll
            for (int c = 0; c < 4; ++c) {
                const float v = ev[c];
                pool[j][c] += v;
#pragma unroll
                for (int t = 0; t < T_TYPES; ++t) {
                    acc[t]           = fmaf(v, wS[j][c][t], acc[t]);
                    acc[T_TYPES + t] = fmaf(v, wE[j][c][t], acc[T_TYPES + t]);
                }
            }
        }

        // 64-lane butterfly: every lane ends with the full sum of each acc
#pragma unroll
        for (int a = 0; a < 12; ++a) {
#pragma unroll
            for (int m = 1; m < 64; m <<= 1)
                acc[a] += __shfl_xor(acc[a], m, 64);
        }

        // per-lane value select (lane a -> acc[a]), identical to round 1
        float v = acc[0];
#pragma unroll
        for (int a = 1; a < 12; ++a) v = (lane == a) ? acc[a] : v;
        v += myBias;

        if (lane < T_TYPES) {
            // online softmax + top3 for type = lane
            if (v > M) {
                se = se * expf(M - v) + 1.0f;
                v2 = v1; i2 = i1; v1 = v0; i1 = i0; v0 = v; i0 = r;
                M = v;
            } else {
                se += expf(v - M);
                if (v > v2 || (v == v2 && r < i2)) {
                    if (v > v1 || (v == v1 && r < i1)) {
                        v2 = v1; i2 = i1; v1 = v; i1 = r;
                    } else { v2 = v; i2 = r; }
                }
            }
        } else if (lane < 2 * T_TYPES) {
            endS[(size_t)(lane - T_TYPES) * S_TOK + r] = v;
        }

        c0 = n0; c1 = n1; c2 = n2; rowp = nextp;
    }

    if (lane < T_TYPES) {
        float* p = partials + ((size_t)wave * T_TYPES + lane) * 8;
        p[0] = M;  p[1] = se; p[2] = v0; p[3] = v1; p[4] = v2;
        p[5] = __int_as_float(i0);
        p[6] = __int_as_float(i1);
        p[7] = __int_as_float(i2);
    }

    // block-reduce pooled partials
    __shared__ float lds[4][H_DIM];
#pragma unroll
    for (int j = 0; j < 3; ++j) {
        float4 pv = make_float4(pool[j][0], pool[j][1], pool[j][2], pool[j][3]);
        ((float4*)lds[wib])[lane + 64 * j] = pv;
    }
    __syncthreads();
    for (int h = threadIdx.x; h < H_DIM; h += 256) {
        pooledPart[(size_t)blockIdx.x * H_DIM + h] =
            (lds[0][h] + lds[1][h]) + (lds[2][h] + lds[3][h]);
    }
}

// ---------------------------------------------------------------------------
// Kernel 2 (14 blocks x 1024):
//   blocks 0..5   : combine the 2048 per-wave (M,se,top3) partials of type b
//   blocks 6..13  : hierarchical pooled reduce (64 block-partials each)
// ---------------------------------------------------------------------------
__global__ __launch_bounds__(1024) void k_mid(
    const float* __restrict__ partials,
    const float* __restrict__ pooledPart,
    float* __restrict__ pooled2,        // [POOL_CHUNKS][H_DIM]
    float* __restrict__ res)            // [T_TYPES][8]
{
    const int b = blockIdx.x;
    const int tid = threadIdx.x;

    if (b >= T_TYPES) {
        const int c = b - T_TYPES;
        if (tid < H_DIM) {
            const float* base = pooledPart + (size_t)c * BLK_PER_CHUNK * H_DIM + tid;
            float s0 = 0, s1 = 0, s2 = 0, s3 = 0;
            for (int i = 0; i < BLK_PER_CHUNK; i += 4) {
                s0 += base[(size_t)(i + 0) * H_DIM];
                s1 += base[(size_t)(i + 1) * H_DIM];
                s2 += base[(size_t)(i + 2) * H_DIM];
                s3 += base[(size_t)(i + 3) * H_DIM];
            }
            pooled2[c * H_DIM + tid] = (s0 + s1) + (s2 + s3);
        }
        return;
    }

    float M, se, v0, v1, v2; int i0, i1, i2;
    {
        const float* p = partials + ((size_t)tid * T_TYPES + b) * 8;
        M = p[0]; se = p[1]; v0 = p[2]; v1 = p[3]; v2 = p[4];
        i0 = __float_as_int(p[5]); i1 = __float_as_int(p[6]); i2 = __float_as_int(p[7]);
    }
    {
        const float* p = partials + ((size_t)(tid + 1024) * T_TYPES + b) * 8;
        merge_state(M, se, v0, v1, v2, i0, i1, i2,
                    p[0], p[1], p[2], p[3], p[4],
                    __float_as_int(p[5]), __float_as_int(p[6]), __float_as_int(p[7]));
    }

#pragma unroll
    for (int msk = 1; msk < 64; msk <<= 1) {
        const float Mb  = __shfl_xor(M,  msk, 64);
        const float seb = __shfl_xor(se, msk, 64);
        const float w0  = __shfl_xor(v0, msk, 64);
        const float w1  = __shfl_xor(v1, msk, 64);
        const float w2  = __shfl_xor(v2, msk, 64);
        const int   j0  = __shfl_xor(i0, msk, 64);
        const int   j1  = __shfl_xor(i1, msk, 64);
        const int   j2  = __shfl_xor(i2, msk, 64);
        merge_state(M, se, v0, v1, v2, i0, i1, i2, Mb, seb, w0, w1, w2, j0, j1, j2);
    }

    __shared__ float sm[16][8];
    if ((tid & 63) == 0) {
        const int w = tid >> 6;
        sm[w][0] = M;  sm[w][1] = se;
        sm[w][2] = v0; sm[w][3] = v1; sm[w][4] = v2;
        sm[w][5] = __int_as_float(i0);
        sm[w][6] = __int_as_float(i1);
        sm[w][7] = __int_as_float(i2);
    }
    __syncthreads();
    if (tid == 0) {
        for (int w = 1; w < 16; ++w) {
            merge_state(M, se, v0, v1, v2, i0, i1, i2,
                        sm[w][0], sm[w][1], sm[w][2], sm[w][3], sm[w][4],
                        __float_as_int(sm[w][5]), __float_as_int(sm[w][6]),
                        __float_as_int(sm[w][7]));
        }
        float* r = res + b * 8;
        r[0] = v0; r[1] = v1; r[2] = v2;
        r[3] = __int_as_float(i0);
        r[4] = __int_as_float(i1);
        r[5] = __int_as_float(i2);
        r[6] = M; r[7] = se;
    }
}

// ---------------------------------------------------------------------------
// Kernel 3: single small block. pooled -> GELU MLP -> sigmoid; softmax
// top-vals from (M,SE); 15-wide window argmax; write all 72 f32 outputs.
// ---------------------------------------------------------------------------
__global__ __launch_bounds__(256) void k_final(
    const float* __restrict__ pooled2,
    const float* __restrict__ W1, const float* __restrict__ b1,
    const float* __restrict__ W2, const float* __restrict__ b2,
    const float* __restrict__ endS, const float* __restrict__ res,
    float* __restrict__ out)
{
    const int tid = threadIdx.x;
    __shared__ float pl[H_DIM];
    for (int h = tid; h < H_DIM; h += 256) {
        float s = 0.0f;
#pragma unroll
        for (int c = 0; c < POOL_CHUNKS; ++c) s += pooled2[c * H_DIM + h];
        pl[h] = s * (1.0f / (float)S_TOK);
    }
    __syncthreads();

    __shared__ float hpart[4][64];
    {
        const int o = tid & 63, part = tid >> 6;
        const float* w = W1 + o;
        float z = 0.0f;
        for (int h = part * 192; h < part * 192 + 192; ++h)
            z = fmaf(pl[h], w[(size_t)h * 64], z);
        hpart[part][o] = z;
    }
    __syncthreads();

    __shared__ float hdn[64];
    if (tid < 64) {
        const float z = b1[tid] +
            ((hpart[0][tid] + hpart[1][tid]) + (hpart[2][tid] + hpart[3][tid]));
        hdn[tid] = 0.5f * z * (1.0f + erff(z * 0.7071067811865475f));
    }
    __syncthreads();

    __shared__ float tconf[T_TYPES];
    if (tid < T_TYPES) {
        float z = b2[tid];
        for (int i = 0; i < 64; ++i) z = fmaf(hdn[i], W2[i * T_TYPES + tid], z);
        tconf[tid] = 1.0f / (1.0f + expf(-z));
    }
    __syncthreads();

    if (tid < T_TYPES * K_TOP) {
        const int t = tid / K_TOP;
        const int k = tid % K_TOP;
        const float* r = res + t * 8;
        const float vraw = r[k];
        const int   idx  = __float_as_int(r[3 + k]);
        const float M    = r[6];
        const float SE   = r[7];
        const float prob = expf(vraw - M) / SE;

        const float* ecol = endS + (size_t)t * S_TOK;
        float best = -3.402823466e38f;
        int   boff = 0;
#pragma unroll
        for (int w = 0; w < WIN; ++w) {
            const int pos = idx + w;
            if (pos < S_TOK) {
                const float ev = ecol[pos];
                if (ev > best) { best = ev; boff = w; }
            }
        }
        const float tc = tconf[t];
        const bool valid = (tc >= 0.3f) && (prob >= 0.15f);
        out[tid]      = valid ? prob * tc : 0.0f;
        out[18 + tid] = (float)idx;
        out[36 + tid] = (float)(idx + boff + 1);
        out[54 + tid] = valid ? 1.0f : 0.0f;
    }
}

extern "C" void kernel_launch(void* const* d_in, const int* in_sizes, int n_in,
                              void* d_out, int out_size, void* d_ws, size_t ws_size,
                              hipStream_t stream)
{
    const float* emb    = (const float*)d_in[0];
    const float* Wstart = (const float*)d_in[1];
    const float* bstart = (const float*)d_in[2];
    const float* Wend   = (const float*)d_in[3];
    const float* bend   = (const float*)d_in[4];
    const float* W1     = (const float*)d_in[5];
    const float* b1     = (const float*)d_in[6];
    const float* W2     = (const float*)d_in[7];
    const float* b2     = (const float*)d_in[8];
    float* out = (float*)d_out;

    // workspace layout (floats)
    float* ws       = (float*)d_ws;
    float* endS     = ws;                                          // 6*65536
    float* partials = endS + (size_t)T_TYPES * S_TOK;              // 2048*6*8
    float* pp       = partials + (size_t)NWAVES * T_TYPES * 8;     // 512*768
    float* pooled2  = pp + (size_t)NBLK1 * H_DIM;                  // 8*768
    float* res      = pooled2 + (size_t)POOL_CHUNKS * H_DIM;       // 6*8

    k_scores<<<NBLK1, 256, 0, stream>>>(emb, Wstart, bstart, Wend, bend,
                                        endS, partials, pp);
    k_mid<<<T_TYPES + POOL_CHUNKS, 1024, 0, stream>>>(partials, pp, pooled2, res);
    k_final<<<1, 256, 0, stream>>>(pooled2, W1, b1, W2, b2, endS, res, out);
}

// Round 3
// 340.953 us; speedup vs baseline: 1.3172x; 1.0240x over previous
//
#include <hip/hip_runtime.h>
#include <math.h>

#define S_TOK 65536
#define H_DIM 768
#define T_TYPES 6
#define K_TOP 3
#define WIN 15
#define NBLK1 512
#define NWAVES (NBLK1 * 4)               // 2048
#define ROWS_PER_WAVE (S_TOK / NWAVES)   // 32
#define POOL_CHUNKS 8
#define BLK_PER_CHUNK (NBLK1 / POOL_CHUNKS)  // 64

// ---------------------------------------------------------------------------
// top-3 insert with jnp tie-breaking (equal value -> lower index wins)
// ---------------------------------------------------------------------------
__device__ __forceinline__ void top3_insert(float v, int i,
    float& v0, float& v1, float& v2, int& i0, int& i1, int& i2)
{
    if (v > v0 || (v == v0 && i < i0)) {
        v2 = v1; i2 = i1; v1 = v0; i1 = i0; v0 = v; i0 = i;
    } else if (v > v1 || (v == v1 && i < i1)) {
        v2 = v1; i2 = i1; v1 = v; i1 = i;
    } else if (v > v2 || (v == v2 && i < i2)) {
        v2 = v; i2 = i;
    }
}

__device__ __forceinline__ void merge_state(
    float& M, float& se, float& v0, float& v1, float& v2,
    int& i0, int& i1, int& i2,
    float Mb, float seb, float w0, float w1, float w2,
    int j0, int j1, int j2)
{
    const float Mn = fmaxf(M, Mb);
    se = se * expf(M - Mn) + seb * expf(Mb - Mn);
    M = Mn;
    top3_insert(w0, j0, v0, v1, v2, i0, i1, i2);
    top3_insert(w1, j1, v0, v1, v2, i0, i1, i2);
    top3_insert(w2, j2, v0, v1, v2, i0, i1, i2);
}

// ---------------------------------------------------------------------------
// Kernel 1: single pass over token_embeds (192 MiB). Wave-per-row, next-row
// prefetch. Packed-halving butterfly: 14 shuffles/row instead of 72
// (acc count 12->6->3->2->1 over masks 32,16,8,4, then plain 2,1).
// Designated lane for sem s: lanes {0,4,8,16,20,24} hold start types 0..5
// (online softmax + top3 state), lanes {32,36,40,48,52,56} hold end types
// (stored to endS[T][S]). Per-block pooled partials as before.
// ---------------------------------------------------------------------------
__global__ __launch_bounds__(256, 2) void k_scores(
    const float* __restrict__ emb,
    const float* __restrict__ Wstart, const float* __restrict__ bstart,
    const float* __restrict__ Wend,   const float* __restrict__ bend,
    float* __restrict__ endS,
    float* __restrict__ partials,     // [NWAVES][T_TYPES][8]
    float* __restrict__ pooledPart)   // [NBLK1][H_DIM]
{
    const int lane = threadIdx.x & 63;
    const int wib  = threadIdx.x >> 6;
    const int wave = blockIdx.x * 4 + wib;

    const bool b5 = (lane & 32) != 0;
    const bool b4 = (lane & 16) != 0;
    const bool b3 = (lane & 8)  != 0;
    const bool b2 = (lane & 4)  != 0;
    const int  sem = (b5 ? 6 : 0) + (b4 ? 3 : 0) + (b3 ? 2 : (b2 ? 1 : 0));
    const bool desig   = ((lane & 3) == 0) && !(b3 && b2);
    const bool isStart = desig && !b5;
    const bool isEnd   = desig && b5;

    float wS[3][4][T_TYPES], wE[3][4][T_TYPES];
#pragma unroll
    for (int j = 0; j < 3; ++j)
#pragma unroll
        for (int c = 0; c < 4; ++c) {
            const int h = 4 * (lane + 64 * j) + c;
#pragma unroll
            for (int t = 0; t < T_TYPES; ++t) {
                wS[j][c][t] = Wstart[h * T_TYPES + t];
                wE[j][c][t] = Wend  [h * T_TYPES + t];
            }
        }

    float myBias = 0.0f;
    if (isStart) myBias = bstart[sem];
    if (isEnd)   myBias = bend[sem - T_TYPES];

    float pool[3][4] = {};

    // online softmax + top3 state (meaningful on designated start lanes)
    float M  = -3.402823466e38f, se = 0.0f;
    float v0 = -3.402823466e38f, v1 = v0, v2 = v0;
    int   i0 = -1, i1 = -1, i2 = -1;

    const int r0 = wave * ROWS_PER_WAVE;
    const float4* rowp = (const float4*)emb + (size_t)r0 * (H_DIM / 4);
    float4 c0 = rowp[lane], c1 = rowp[lane + 64], c2 = rowp[lane + 128];

    for (int r = r0; r < r0 + ROWS_PER_WAVE; ++r) {
        const float4* nextp = rowp + ((r + 1 < S_TOK) ? (H_DIM / 4) : 0);
        float4 n0 = nextp[lane], n1 = nextp[lane + 64], n2 = nextp[lane + 128];

        float acc[12];
#pragma unroll
        for (int a = 0; a < 12; ++a) acc[a] = 0.0f;

        const float4 ee[3] = {c0, c1, c2};
#pragma unroll
        for (int j = 0; j < 3; ++j) {
            const float ev[4] = {ee[j].x, ee[j].y, ee[j].z, ee[j].w};
#pragma unroll
            for (int c = 0; c < 4; ++c) {
                const float v = ev[c];
                pool[j][c] += v;
#pragma unroll
                for (int t = 0; t < T_TYPES; ++t) {
                    acc[t]           = fmaf(v, wS[j][c][t], acc[t]);
                    acc[T_TYPES + t] = fmaf(v, wE[j][c][t], acc[T_TYPES + t]);
                }
            }
        }

        // ---- packed-halving butterfly: 14 shuffles total ----
        // step 1 (mask 32): 12 -> 6, sem = 6*b5 + t
        float na[6];
#pragma unroll
        for (int t = 0; t < 6; ++t) {
            const float snd  = b5 ? acc[t] : acc[t + 6];
            const float keep = b5 ? acc[t + 6] : acc[t];
            na[t] = keep + __shfl_xor(snd, 32, 64);
        }
        // step 2 (mask 16): 6 -> 3, sem = 6*b5 + 3*b4 + t
        float nb[3];
#pragma unroll
        for (int t = 0; t < 3; ++t) {
            const float snd  = b4 ? na[t] : na[t + 3];
            const float keep = b4 ? na[t + 3] : na[t];
            nb[t] = keep + __shfl_xor(snd, 16, 64);
        }
        // step 3 (mask 8): 3 -> 2. nc0: b3=0 -> sem s+0, b3=1 -> sem s+2.
        // nc1: sem s+1 on all lanes.
        float nc0, nc1;
        {
            const float snd  = b3 ? nb[2] : nb[0];   // partner receives what it keeps
            const float keep = b3 ? nb[2] : nb[0];
            nc0 = keep + __shfl_xor(b3 ? nb[0] : nb[2], 8, 64);
            // b3=0 keeps nb[0], partner (b3=1) must send nb[0]; b3=1 keeps nb[2],
            // partner (b3=0) must send nb[2]:
            (void)snd;
            nc1 = nb[1] + __shfl_xor(nb[1], 8, 64);
        }
        // step 4 (mask 4): 2 -> 1. d sem = 6b5+3b4+(b3?2:b2)
        float d;
        {
            const float snd  = (b3 || b2) ? nc0 : nc1;
            const float keep = (!b3 && b2) ? nc1 : nc0;
            d = keep + __shfl_xor(snd, 4, 64);
        }
        // steps 5,6: plain
        d += __shfl_xor(d, 2, 64);
        d += __shfl_xor(d, 1, 64);

        const float v = d + myBias;

        if (isStart) {
            if (v > M) {
                se = se * expf(M - v) + 1.0f;
                v2 = v1; i2 = i1; v1 = v0; i1 = i0; v0 = v; i0 = r;
                M = v;
            } else {
                se += expf(v - M);
                if (v > v2 || (v == v2 && r < i2)) {
                    if (v > v1 || (v == v1 && r < i1)) {
                        v2 = v1; i2 = i1; v1 = v; i1 = r;
                    } else { v2 = v; i2 = r; }
                }
            }
        } else if (isEnd) {
            endS[(size_t)(sem - T_TYPES) * S_TOK + r] = v;
        }

        c0 = n0; c1 = n1; c2 = n2; rowp = nextp;
    }

    if (isStart) {
        float* p = partials + ((size_t)wave * T_TYPES + sem) * 8;
        p[0] = M;  p[1] = se; p[2] = v0; p[3] = v1; p[4] = v2;
        p[5] = __int_as_float(i0);
        p[6] = __int_as_float(i1);
        p[7] = __int_as_float(i2);
    }

    // block-reduce pooled partials
    __shared__ float lds[4][H_DIM];
#pragma unroll
    for (int j = 0; j < 3; ++j) {
        float4 pv = make_float4(pool[j][0], pool[j][1], pool[j][2], pool[j][3]);
        ((float4*)lds[wib])[lane + 64 * j] = pv;
    }
    __syncthreads();
    for (int h = threadIdx.x; h < H_DIM; h += 256) {
        pooledPart[(size_t)blockIdx.x * H_DIM + h] =
            (lds[0][h] + lds[1][h]) + (lds[2][h] + lds[3][h]);
    }
}

// ---------------------------------------------------------------------------
// Kernel 2 (14 blocks x 1024):
//   blocks 0..5  : combine 2048 per-wave (M,se,top3) partials of type b
//   blocks 6..13 : pooled chunk reduce (64 block-partials) AND the chunk's
//                  W1 GEMV partial z[c][64] (pulls the 192 KB W1 read and the
//                  serial GEMV chains out of the single-block k_final)
// ---------------------------------------------------------------------------
__global__ __launch_bounds__(1024) void k_mid(
    const float* __restrict__ partials,
    const float* __restrict__ pooledPart,
    const float* __restrict__ W1,
    float* __restrict__ zpart,          // [POOL_CHUNKS][64]
    float* __restrict__ res)            // [T_TYPES][8]
{
    const int b = blockIdx.x;
    const int tid = threadIdx.x;

    if (b >= T_TYPES) {
        const int c = b - T_TYPES;
        __shared__ float pl[H_DIM];
        if (tid < H_DIM) {
            const float* base = pooledPart + (size_t)c * BLK_PER_CHUNK * H_DIM + tid;
            float s0 = 0, s1 = 0, s2 = 0, s3 = 0;
            for (int i = 0; i < BLK_PER_CHUNK; i += 4) {
                s0 += base[(size_t)(i + 0) * H_DIM];
                s1 += base[(size_t)(i + 1) * H_DIM];
                s2 += base[(size_t)(i + 2) * H_DIM];
                s3 += base[(size_t)(i + 3) * H_DIM];
            }
            pl[tid] = (s0 + s1) + (s2 + s3);
        }
        __syncthreads();
        // z[c][o] = sum_h pl[h] * W1[h][o], 16 segments x 48 h each
        const int o = tid & 63, seg = tid >> 6;
        float z = 0.0f;
        const int h0 = seg * 48;
        for (int i = 0; i < 48; ++i)
            z = fmaf(pl[h0 + i], W1[(size_t)(h0 + i) * 64 + o], z);
        __shared__ float zred[16][64];
        zred[seg][o] = z;
        __syncthreads();
        if (tid < 64) {
            float s = 0.0f;
#pragma unroll
            for (int g = 0; g < 16; ++g) s += zred[g][tid];
            zpart[c * 64 + tid] = s;
        }
        return;
    }

    float M, se, v0, v1, v2; int i0, i1, i2;
    {
        const float* p = partials + ((size_t)tid * T_TYPES + b) * 8;
        M = p[0]; se = p[1]; v0 = p[2]; v1 = p[3]; v2 = p[4];
        i0 = __float_as_int(p[5]); i1 = __float_as_int(p[6]); i2 = __float_as_int(p[7]);
    }
    {
        const float* p = partials + ((size_t)(tid + 1024) * T_TYPES + b) * 8;
        merge_state(M, se, v0, v1, v2, i0, i1, i2,
                    p[0], p[1], p[2], p[3], p[4],
                    __float_as_int(p[5]), __float_as_int(p[6]), __float_as_int(p[7]));
    }

#pragma unroll
    for (int msk = 1; msk < 64; msk <<= 1) {
        const float Mb  = __shfl_xor(M,  msk, 64);
        const float seb = __shfl_xor(se, msk, 64);
        const float w0  = __shfl_xor(v0, msk, 64);
        const float w1  = __shfl_xor(v1, msk, 64);
        const float w2  = __shfl_xor(v2, msk, 64);
        const int   j0  = __shfl_xor(i0, msk, 64);
        const int   j1  = __shfl_xor(i1, msk, 64);
        const int   j2  = __shfl_xor(i2, msk, 64);
        merge_state(M, se, v0, v1, v2, i0, i1, i2, Mb, seb, w0, w1, w2, j0, j1, j2);
    }

    __shared__ float sm[16][8];
    if ((tid & 63) == 0) {
        const int w = tid >> 6;
        sm[w][0] = M;  sm[w][1] = se;
        sm[w][2] = v0; sm[w][3] = v1; sm[w][4] = v2;
        sm[w][5] = __int_as_float(i0);
        sm[w][6] = __int_as_float(i1);
        sm[w][7] = __int_as_float(i2);
    }
    __syncthreads();
    if (tid == 0) {
        for (int w = 1; w < 16; ++w) {
            merge_state(M, se, v0, v1, v2, i0, i1, i2,
                        sm[w][0], sm[w][1], sm[w][2], sm[w][3], sm[w][4],
                        __float_as_int(sm[w][5]), __float_as_int(sm[w][6]),
                        __float_as_int(sm[w][7]));
        }
        float* r = res + b * 8;
        r[0] = v0; r[1] = v1; r[2] = v2;
        r[3] = __int_as_float(i0);
        r[4] = __int_as_float(i1);
        r[5] = __int_as_float(i2);
        r[6] = M; r[7] = se;
    }
}

// ---------------------------------------------------------------------------
// Kernel 3: tiny epilogue. z-sum -> GELU -> W2 -> sigmoid; softmax top-vals
// from (M,SE); 15-wide window argmax; write all 72 f32 outputs.
// ---------------------------------------------------------------------------
__global__ __launch_bounds__(256) void k_final(
    const float* __restrict__ zpart,
    const float* __restrict__ b1,
    const float* __restrict__ W2, const float* __restrict__ b2,
    const float* __restrict__ endS, const float* __restrict__ res,
    float* __restrict__ out)
{
    const int tid = threadIdx.x;
    __shared__ float hdn[64];
    if (tid < 64) {
        float zs = 0.0f;
#pragma unroll
        for (int c = 0; c < POOL_CHUNKS; ++c) zs += zpart[c * 64 + tid];
        const float z = zs * (1.0f / (float)S_TOK) + b1[tid];
        hdn[tid] = 0.5f * z * (1.0f + erff(z * 0.7071067811865475f));
    }
    __syncthreads();

    __shared__ float tconf[T_TYPES];
    if (tid < T_TYPES) {
        float z = b2[tid];
        for (int i = 0; i < 64; ++i) z = fmaf(hdn[i], W2[i * T_TYPES + tid], z);
        tconf[tid] = 1.0f / (1.0f + expf(-z));
    }
    __syncthreads();

    if (tid < T_TYPES * K_TOP) {
        const int t = tid / K_TOP;
        const int k = tid % K_TOP;
        const float* r = res + t * 8;
        const float vraw = r[k];
        const int   idx  = __float_as_int(r[3 + k]);
        const float M    = r[6];
        const float SE   = r[7];
        const float prob = expf(vraw - M) / SE;

        const float* ecol = endS + (size_t)t * S_TOK;
        float best = -3.402823466e38f;
        int   boff = 0;
#pragma unroll
        for (int w = 0; w < WIN; ++w) {
            const int pos = idx + w;
            if (pos < S_TOK) {
                const float ev = ecol[pos];
                if (ev > best) { best = ev; boff = w; }
            }
        }
        const float tc = tconf[t];
        const bool valid = (tc >= 0.3f) && (prob >= 0.15f);
        out[tid]      = valid ? prob * tc : 0.0f;
        out[18 + tid] = (float)idx;
        out[36 + tid] = (float)(idx + boff + 1);
        out[54 + tid] = valid ? 1.0f : 0.0f;
    }
}

extern "C" void kernel_launch(void* const* d_in, const int* in_sizes, int n_in,
                              void* d_out, int out_size, void* d_ws, size_t ws_size,
                              hipStream_t stream)
{
    const float* emb    = (const float*)d_in[0];
    const float* Wstart = (const float*)d_in[1];
    const float* bstart = (const float*)d_in[2];
    const float* Wend   = (const float*)d_in[3];
    const float* bend   = (const float*)d_in[4];
    const float* W1     = (const float*)d_in[5];
    const float* b1     = (const float*)d_in[6];
    const float* W2     = (const float*)d_in[7];
    const float* b2     = (const float*)d_in[8];
    float* out = (float*)d_out;

    // workspace layout (floats)
    float* ws       = (float*)d_ws;
    float* endS     = ws;                                          // 6*65536
    float* partials = endS + (size_t)T_TYPES * S_TOK;              // 2048*6*8
    float* pp       = partials + (size_t)NWAVES * T_TYPES * 8;     // 512*768
    float* zpart    = pp + (size_t)NBLK1 * H_DIM;                  // 8*64
    float* res      = zpart + (size_t)POOL_CHUNKS * 64;            // 6*8

    k_scores<<<NBLK1, 256, 0, stream>>>(emb, Wstart, bstart, Wend, bend,
                                        endS, partials, pp);
    k_mid<<<T_TYPES + POOL_CHUNKS, 1024, 0, stream>>>(partials, pp, W1, zpart, res);
    k_final<<<1, 256, 0, stream>>>(zpart, b1, W2, b2, endS, res, out);
}